// Round 1
// baseline (5671.002 us; speedup 1.0000x reference)
//
#include <hip/hip_runtime.h>

#define NODES 100000
#define EDGES 1600000

// ---------------------------------------------------------------------------
// copy float4: out = in  (used to init agg accumulator with self-feature x)
// ---------------------------------------------------------------------------
__global__ __launch_bounds__(256) void copy_f4(const float4* __restrict__ in,
                                               float4* __restrict__ out, int n4) {
  int i = blockIdx.x * 256 + threadIdx.x;
  if (i < n4) out[i] = in[i];
}

// ---------------------------------------------------------------------------
// scatter-add: agg[dst[e], :] += x[src[e], :]   (128 features, fp32)
// 32 lanes per edge, float4 per lane, 4 fp32 atomics per lane.
// ---------------------------------------------------------------------------
__global__ __launch_bounds__(256) void scatter_add128(
    const float* __restrict__ x, const int* __restrict__ src,
    const int* __restrict__ dst, float* __restrict__ agg) {
  long long gtid = (long long)blockIdx.x * 256 + threadIdx.x;
  int e = (int)(gtid >> 5);
  if (e >= EDGES) return;
  int lane = (int)(gtid & 31);
  int s = src[e];
  int d = dst[e];
  float4 v = ((const float4*)x)[(size_t)s * 32 + lane];
  float* p = agg + (size_t)d * 128 + lane * 4;
  atomicAdd(p + 0, v.x);
  atomicAdd(p + 1, v.y);
  atomicAdd(p + 2, v.z);
  atomicAdd(p + 3, v.w);
}

// ---------------------------------------------------------------------------
// C[M,N] = relu(A[M,K] @ W[K,N] + bias)   fp32, register-blocked.
// Block: 256 threads, BM=64 rows. Each thread: TM rows x 4 cols.
// A tile staged in LDS; W read from global (tiny, L2-hot).
// ---------------------------------------------------------------------------
template <int K, int N>
__global__ __launch_bounds__(256) void gemm_bias_relu(
    const float* __restrict__ A, const float* __restrict__ W,
    const float* __restrict__ bias, float* __restrict__ C, int M) {
  constexpr int BM = 64;
  constexpr int CG = N / 4;        // col groups (float4 wide)
  constexpr int TY = 256 / CG;     // row-threads
  constexpr int TM = BM / TY;      // rows per thread
  __shared__ float As[BM * K];

  const int tid = threadIdx.x;
  const int rowBase = blockIdx.x * BM;

  // stage A tile (zero-pad rows past M)
  constexpr int totalV4 = BM * K / 4;
  for (int i = tid; i < totalV4; i += 256) {
    int r = i / (K / 4), c = i % (K / 4);
    float4 v = make_float4(0.f, 0.f, 0.f, 0.f);
    if (rowBase + r < M)
      v = ((const float4*)A)[(size_t)(rowBase + r) * (K / 4) + c];
    *(float4*)&As[r * K + c * 4] = v;
  }
  __syncthreads();

  const int tx = tid % CG;
  const int ty = tid / CG;
  float acc[TM][4];
#pragma unroll
  for (int i = 0; i < TM; i++)
    acc[i][0] = acc[i][1] = acc[i][2] = acc[i][3] = 0.f;

  const float4* W4 = (const float4*)W;
  for (int k = 0; k < K; k += 4) {
    float4 w0 = W4[(k + 0) * CG + tx];
    float4 w1 = W4[(k + 1) * CG + tx];
    float4 w2 = W4[(k + 2) * CG + tx];
    float4 w3 = W4[(k + 3) * CG + tx];
#pragma unroll
    for (int i = 0; i < TM; i++) {
      float4 a = *(const float4*)&As[(ty * TM + i) * K + k];
      acc[i][0] += a.x * w0.x + a.y * w1.x + a.z * w2.x + a.w * w3.x;
      acc[i][1] += a.x * w0.y + a.y * w1.y + a.z * w2.y + a.w * w3.y;
      acc[i][2] += a.x * w0.z + a.y * w1.z + a.z * w2.z + a.w * w3.z;
      acc[i][3] += a.x * w0.w + a.y * w1.w + a.z * w2.w + a.w * w3.w;
    }
  }

  float4 bv = ((const float4*)bias)[tx];
#pragma unroll
  for (int i = 0; i < TM; i++) {
    int r = rowBase + ty * TM + i;
    if (r < M) {
      float4 o;
      o.x = fmaxf(acc[i][0] + bv.x, 0.f);
      o.y = fmaxf(acc[i][1] + bv.y, 0.f);
      o.z = fmaxf(acc[i][2] + bv.z, 0.f);
      o.w = fmaxf(acc[i][3] + bv.w, 0.f);
      ((float4*)C)[(size_t)r * CG + tx] = o;
    }
  }
}

// ---------------------------------------------------------------------------
// launch
// ---------------------------------------------------------------------------
extern "C" void kernel_launch(void* const* d_in, const int* in_sizes, int n_in,
                              void* d_out, int out_size, void* d_ws, size_t ws_size,
                              hipStream_t stream) {
  const float* x = (const float*)d_in[0];
  const int* ei = (const int*)d_in[1];
  const int* src = ei;               // edge_index[0]
  const int* dst = ei + EDGES;       // edge_index[1]
  const float* W1 = (const float*)d_in[2];
  const float* b1 = (const float*)d_in[3];
  const float* W2 = (const float*)d_in[4];
  const float* b2 = (const float*)d_in[5];
  const float* W3 = (const float*)d_in[6];
  const float* b3 = (const float*)d_in[7];
  const float* W4 = (const float*)d_in[8];
  const float* b4 = (const float*)d_in[9];
  float* out = (float*)d_out;

  char* ws = (char*)d_ws;
  float* bufA = (float*)ws;                                   // 100000*128 f32
  float* bufB = (float*)(ws + (size_t)NODES * 128 * 4);       // 100000*128 f32
  float* bufC = (float*)(ws + (size_t)NODES * 128 * 4 * 2);   // 100000*64  f32

  const int n4 = NODES * 128 / 4;
  const int cblocks = (n4 + 255) / 256;
  const int sblocks = (int)(((long long)EDGES * 32 + 255) / 256);
  const int gblocks = (NODES + 63) / 64;

  // ---- layer 1 ----
  copy_f4<<<cblocks, 256, 0, stream>>>((const float4*)x, (float4*)bufA, n4);
  scatter_add128<<<sblocks, 256, 0, stream>>>(x, src, dst, bufA);           // h_pre1 = x + sum x[src]
  gemm_bias_relu<128, 128><<<gblocks, 256, 0, stream>>>(bufA, W1, b1, bufB, NODES);  // t1
  gemm_bias_relu<128, 128><<<gblocks, 256, 0, stream>>>(bufB, W2, b2, bufA, NODES);  // h1 (outer relu fused)

  // ---- layer 2 ----
  copy_f4<<<cblocks, 256, 0, stream>>>((const float4*)bufA, (float4*)bufB, n4);
  scatter_add128<<<sblocks, 256, 0, stream>>>(bufA, src, dst, bufB);        // h_pre2 = h1 + sum h1[src]
  gemm_bias_relu<128, 64><<<gblocks, 256, 0, stream>>>(bufB, W3, b3, bufC, NODES);   // t2
  gemm_bias_relu<64, 64><<<gblocks, 256, 0, stream>>>(bufC, W4, b4, out, NODES);     // out (outer relu fused)
}

// Round 2
// 860.847 us; speedup vs baseline: 6.5877x; 6.5877x over previous
//
#include <hip/hip_runtime.h>

#define NODES 100000
#define EDGES 1600000

// ---------------------------------------------------------------------------
// zero n ints
// ---------------------------------------------------------------------------
__global__ __launch_bounds__(256) void zero_ints(int* __restrict__ p, int n) {
  int i = blockIdx.x * 256 + threadIdx.x;
  if (i < n) p[i] = 0;
}

// ---------------------------------------------------------------------------
// CSR build step 1: histogram of dst
// ---------------------------------------------------------------------------
__global__ __launch_bounds__(256) void hist_dst(const int* __restrict__ dst,
                                                int* __restrict__ deg) {
  int e = blockIdx.x * 256 + threadIdx.x;
  if (e < EDGES) atomicAdd(&deg[dst[e]], 1);
}

// ---------------------------------------------------------------------------
// CSR build step 2: exclusive scan deg -> rowstart (single block, 1024 thr)
// ---------------------------------------------------------------------------
__global__ __launch_bounds__(1024) void scan_deg(const int* __restrict__ deg,
                                                 int* __restrict__ rowstart) {
  constexpr int CHUNK = (NODES + 1023) / 1024;  // 98
  __shared__ int sdata[1024];
  const int tid = threadIdx.x;
  const int beg = tid * CHUNK;
  const int end = min(beg + CHUNK, NODES);

  int total = 0;
  for (int i = beg; i < end; ++i) total += deg[i];
  sdata[tid] = total;
  __syncthreads();

  // Hillis-Steele inclusive scan over 1024 thread totals
  for (int off = 1; off < 1024; off <<= 1) {
    int v = (tid >= off) ? sdata[tid - off] : 0;
    __syncthreads();
    sdata[tid] += v;
    __syncthreads();
  }
  int run = sdata[tid] - total;  // exclusive prefix for this thread's chunk
  for (int i = beg; i < end; ++i) {
    rowstart[i] = run;
    run += deg[i];
  }
  if (tid == 1023) rowstart[NODES] = sdata[1023];
}

// ---------------------------------------------------------------------------
// CSR build step 3: fill buckets  bucket[rowstart[d] + cursor[d]++] = src
// ---------------------------------------------------------------------------
__global__ __launch_bounds__(256) void fill_buckets(
    const int* __restrict__ src, const int* __restrict__ dst,
    const int* __restrict__ rowstart, int* __restrict__ cursor,
    int* __restrict__ bucket) {
  int e = blockIdx.x * 256 + threadIdx.x;
  if (e >= EDGES) return;
  int d = dst[e];
  int pos = atomicAdd(&cursor[d], 1);
  bucket[rowstart[d] + pos] = src[e];
}

// ---------------------------------------------------------------------------
// gather aggregation: out[n,:] = x[n,:] + sum_{j in in(n)} x[src_j,:]
// One wave (64 lanes) per node; each lane owns 2 of the 128 features.
// ---------------------------------------------------------------------------
__global__ __launch_bounds__(256) void gather_sum128(
    const float* __restrict__ x, const int* __restrict__ rowstart,
    const int* __restrict__ bucket, float* __restrict__ out) {
  const int n = blockIdx.x * 4 + (threadIdx.x >> 6);
  if (n >= NODES) return;
  const int lane = threadIdx.x & 63;
  const float2* x2 = (const float2*)x;

  float2 acc = x2[(size_t)n * 64 + lane];
  const int beg = rowstart[n];
  const int end = rowstart[n + 1];
  int j = beg;
  for (; j + 1 < end; j += 2) {
    int s0 = bucket[j];
    int s1 = bucket[j + 1];
    float2 v0 = x2[(size_t)s0 * 64 + lane];
    float2 v1 = x2[(size_t)s1 * 64 + lane];
    acc.x += v0.x + v1.x;
    acc.y += v0.y + v1.y;
  }
  if (j < end) {
    int s = bucket[j];
    float2 v = x2[(size_t)s * 64 + lane];
    acc.x += v.x;
    acc.y += v.y;
  }
  ((float2*)out)[(size_t)n * 64 + lane] = acc;
}

// ---------------------------------------------------------------------------
// C[M,N] = relu(A[M,K] @ W[K,N] + bias)   fp32, register-blocked.
// ---------------------------------------------------------------------------
template <int K, int N>
__global__ __launch_bounds__(256) void gemm_bias_relu(
    const float* __restrict__ A, const float* __restrict__ W,
    const float* __restrict__ bias, float* __restrict__ C, int M) {
  constexpr int BM = 64;
  constexpr int CG = N / 4;        // col groups (float4 wide)
  constexpr int TY = 256 / CG;     // row-threads
  constexpr int TM = BM / TY;      // rows per thread
  __shared__ float As[BM * K];

  const int tid = threadIdx.x;
  const int rowBase = blockIdx.x * BM;

  constexpr int totalV4 = BM * K / 4;
  for (int i = tid; i < totalV4; i += 256) {
    int r = i / (K / 4), c = i % (K / 4);
    float4 v = make_float4(0.f, 0.f, 0.f, 0.f);
    if (rowBase + r < M)
      v = ((const float4*)A)[(size_t)(rowBase + r) * (K / 4) + c];
    *(float4*)&As[r * K + c * 4] = v;
  }
  __syncthreads();

  const int tx = tid % CG;
  const int ty = tid / CG;
  float acc[TM][4];
#pragma unroll
  for (int i = 0; i < TM; i++)
    acc[i][0] = acc[i][1] = acc[i][2] = acc[i][3] = 0.f;

  const float4* W4 = (const float4*)W;
  for (int k = 0; k < K; k += 4) {
    float4 w0 = W4[(k + 0) * CG + tx];
    float4 w1 = W4[(k + 1) * CG + tx];
    float4 w2 = W4[(k + 2) * CG + tx];
    float4 w3 = W4[(k + 3) * CG + tx];
#pragma unroll
    for (int i = 0; i < TM; i++) {
      float4 a = *(const float4*)&As[(ty * TM + i) * K + k];
      acc[i][0] += a.x * w0.x + a.y * w1.x + a.z * w2.x + a.w * w3.x;
      acc[i][1] += a.x * w0.y + a.y * w1.y + a.z * w2.y + a.w * w3.y;
      acc[i][2] += a.x * w0.z + a.y * w1.z + a.z * w2.z + a.w * w3.z;
      acc[i][3] += a.x * w0.w + a.y * w1.w + a.z * w2.w + a.w * w3.w;
    }
  }

  float4 bv = ((const float4*)bias)[tx];
#pragma unroll
  for (int i = 0; i < TM; i++) {
    int r = rowBase + ty * TM + i;
    if (r < M) {
      float4 o;
      o.x = fmaxf(acc[i][0] + bv.x, 0.f);
      o.y = fmaxf(acc[i][1] + bv.y, 0.f);
      o.z = fmaxf(acc[i][2] + bv.z, 0.f);
      o.w = fmaxf(acc[i][3] + bv.w, 0.f);
      ((float4*)C)[(size_t)r * CG + tx] = o;
    }
  }
}

// ---------------------------------------------------------------------------
// launch
// ---------------------------------------------------------------------------
extern "C" void kernel_launch(void* const* d_in, const int* in_sizes, int n_in,
                              void* d_out, int out_size, void* d_ws, size_t ws_size,
                              hipStream_t stream) {
  const float* x = (const float*)d_in[0];
  const int* ei = (const int*)d_in[1];
  const int* src = ei;               // edge_index[0]
  const int* dst = ei + EDGES;       // edge_index[1]
  const float* W1 = (const float*)d_in[2];
  const float* b1 = (const float*)d_in[3];
  const float* W2 = (const float*)d_in[4];
  const float* b2 = (const float*)d_in[5];
  const float* W3 = (const float*)d_in[6];
  const float* b3 = (const float*)d_in[7];
  const float* W4 = (const float*)d_in[8];
  const float* b4 = (const float*)d_in[9];
  float* out = (float*)d_out;

  // workspace layout (~110 MB)
  float* bufA = (float*)d_ws;                        // 100000*128 f32 (51.2 MB)
  float* bufB = bufA + (size_t)NODES * 128;          // 100000*128 f32 (51.2 MB)
  int* rowstart = (int*)(bufB + (size_t)NODES * 128);// 100001 ints
  int* deg = rowstart + NODES + 1;                   // 100000 ints
  int* cursor = deg + NODES;                         // 100000 ints (contiguous w/ deg)
  int* bucket = cursor + NODES;                      // 1.6M ints (6.4 MB)
  float* bufC = bufA;  // t2 (100000*64) reuses bufA — h1 dead after gather2

  const int eblocks = (EDGES + 255) / 256;
  const int nblocks4 = (NODES + 3) / 4;   // gather: 4 nodes (waves) per block
  const int gblocks = (NODES + 63) / 64;

  // ---- build CSR (once; shared by both layers) ----
  zero_ints<<<(2 * NODES + 255) / 256, 256, 0, stream>>>(deg, 2 * NODES);  // deg+cursor
  hist_dst<<<eblocks, 256, 0, stream>>>(dst, deg);
  scan_deg<<<1, 1024, 0, stream>>>(deg, rowstart);
  fill_buckets<<<eblocks, 256, 0, stream>>>(src, dst, rowstart, cursor, bucket);

  // ---- layer 1 ----
  gather_sum128<<<nblocks4, 256, 0, stream>>>(x, rowstart, bucket, bufA);            // h_pre1
  gemm_bias_relu<128, 128><<<gblocks, 256, 0, stream>>>(bufA, W1, b1, bufB, NODES);  // t1
  gemm_bias_relu<128, 128><<<gblocks, 256, 0, stream>>>(bufB, W2, b2, bufA, NODES);  // h1 (outer relu fused)

  // ---- layer 2 ----
  gather_sum128<<<nblocks4, 256, 0, stream>>>(bufA, rowstart, bucket, bufB);         // h_pre2
  gemm_bias_relu<128, 64><<<gblocks, 256, 0, stream>>>(bufB, W3, b3, bufC, NODES);   // t2
  gemm_bias_relu<64, 64><<<gblocks, 256, 0, stream>>>(bufC, W4, b4, out, NODES);     // out
}

// Round 3
// 711.274 us; speedup vs baseline: 7.9730x; 1.2103x over previous
//
#include <hip/hip_runtime.h>

#define NODES 100000
#define EDGES 1600000
#define TILE 1024                       // scan tile (elements)
#define NTILES ((NODES + TILE - 1) / TILE)  // 98

// ---------------------------------------------------------------------------
// zero n ints
// ---------------------------------------------------------------------------
__global__ __launch_bounds__(256) void zero_ints(int* __restrict__ p, int n) {
  int i = blockIdx.x * 256 + threadIdx.x;
  if (i < n) p[i] = 0;
}

// ---------------------------------------------------------------------------
// CSR build step 1: histogram of dst
// ---------------------------------------------------------------------------
__global__ __launch_bounds__(256) void hist_dst(const int* __restrict__ dst,
                                                int* __restrict__ deg) {
  int e = blockIdx.x * 256 + threadIdx.x;
  if (e < EDGES) atomicAdd(&deg[dst[e]], 1);
}

// ---------------------------------------------------------------------------
// CSR build step 2a: per-tile sums (98 blocks x 256 thr, 4 elems/thr)
// ---------------------------------------------------------------------------
__global__ __launch_bounds__(256) void tile_sum(const int* __restrict__ deg,
                                                int* __restrict__ tilesum) {
  __shared__ int s[256];
  const int t = threadIdx.x;
  const int base = blockIdx.x * TILE + t * 4;
  int sum = 0;
#pragma unroll
  for (int k = 0; k < 4; k++) {
    int i = base + k;
    if (i < NODES) sum += deg[i];
  }
  s[t] = sum;
  __syncthreads();
  for (int off = 128; off > 0; off >>= 1) {
    if (t < off) s[t] += s[t + off];
    __syncthreads();
  }
  if (t == 0) tilesum[blockIdx.x] = s[0];
}

// ---------------------------------------------------------------------------
// CSR build step 2b: scan 98 tile sums (1 block x 128 thr)
// ---------------------------------------------------------------------------
__global__ __launch_bounds__(128) void scan_tiles(const int* __restrict__ tilesum,
                                                  int* __restrict__ tileoff,
                                                  int* __restrict__ rowstart) {
  __shared__ int s[128];
  const int t = threadIdx.x;
  int v = (t < NTILES) ? tilesum[t] : 0;
  s[t] = v;
  __syncthreads();
  for (int off = 1; off < 128; off <<= 1) {
    int u = (t >= off) ? s[t - off] : 0;
    __syncthreads();
    s[t] += u;
    __syncthreads();
  }
  if (t < NTILES) tileoff[t] = s[t] - v;  // exclusive
  if (t == 127) rowstart[NODES] = s[127]; // total (== EDGES)
}

// ---------------------------------------------------------------------------
// CSR build step 2c: block-local exclusive scan + tile offset -> rowstart
// ---------------------------------------------------------------------------
__global__ __launch_bounds__(256) void tile_scan(const int* __restrict__ deg,
                                                 const int* __restrict__ tileoff,
                                                 int* __restrict__ rowstart) {
  __shared__ int s[256];
  const int t = threadIdx.x;
  const int base = blockIdx.x * TILE + t * 4;
  int d[4];
  int sum = 0;
#pragma unroll
  for (int k = 0; k < 4; k++) {
    int i = base + k;
    d[k] = (i < NODES) ? deg[i] : 0;
    sum += d[k];
  }
  s[t] = sum;
  __syncthreads();
  for (int off = 1; off < 256; off <<= 1) {
    int u = (t >= off) ? s[t - off] : 0;
    __syncthreads();
    s[t] += u;
    __syncthreads();
  }
  int run = s[t] - sum + tileoff[blockIdx.x];  // exclusive prefix
#pragma unroll
  for (int k = 0; k < 4; k++) {
    int i = base + k;
    if (i < NODES) rowstart[i] = run;
    run += d[k];
  }
}

// ---------------------------------------------------------------------------
// CSR build step 3: fill buckets  bucket[rowstart[d] + cursor[d]++] = src
// ---------------------------------------------------------------------------
__global__ __launch_bounds__(256) void fill_buckets(
    const int* __restrict__ src, const int* __restrict__ dst,
    const int* __restrict__ rowstart, int* __restrict__ cursor,
    int* __restrict__ bucket) {
  int e = blockIdx.x * 256 + threadIdx.x;
  if (e >= EDGES) return;
  int d = dst[e];
  int pos = atomicAdd(&cursor[d], 1);
  bucket[rowstart[d] + pos] = src[e];
}

// ---------------------------------------------------------------------------
// gather aggregation: out[n,:] = x[n,:] + sum_{j in in(n)} x[src_j,:]
// One wave (64 lanes) per node; each lane owns 2 of the 128 features.
// ---------------------------------------------------------------------------
__global__ __launch_bounds__(256) void gather_sum128(
    const float* __restrict__ x, const int* __restrict__ rowstart,
    const int* __restrict__ bucket, float* __restrict__ out) {
  const int n = blockIdx.x * 4 + (threadIdx.x >> 6);
  if (n >= NODES) return;
  const int lane = threadIdx.x & 63;
  const float2* x2 = (const float2*)x;

  float2 acc = x2[(size_t)n * 64 + lane];
  const int beg = rowstart[n];
  const int end = rowstart[n + 1];
  int j = beg;
  for (; j + 1 < end; j += 2) {
    int s0 = bucket[j];
    int s1 = bucket[j + 1];
    float2 v0 = x2[(size_t)s0 * 64 + lane];
    float2 v1 = x2[(size_t)s1 * 64 + lane];
    acc.x += v0.x + v1.x;
    acc.y += v0.y + v1.y;
  }
  if (j < end) {
    int s = bucket[j];
    float2 v = x2[(size_t)s * 64 + lane];
    acc.x += v.x;
    acc.y += v.y;
  }
  ((float2*)out)[(size_t)n * 64 + lane] = acc;
}

// ---------------------------------------------------------------------------
// C[M,N] = relu(A[M,K] @ W[K,N] + bias)   fp32, register-blocked.
// ---------------------------------------------------------------------------
template <int K, int N>
__global__ __launch_bounds__(256) void gemm_bias_relu(
    const float* __restrict__ A, const float* __restrict__ W,
    const float* __restrict__ bias, float* __restrict__ C, int M) {
  constexpr int BM = 64;
  constexpr int CG = N / 4;        // col groups (float4 wide)
  constexpr int TY = 256 / CG;     // row-threads
  constexpr int TM = BM / TY;      // rows per thread
  __shared__ float As[BM * K];

  const int tid = threadIdx.x;
  const int rowBase = blockIdx.x * BM;

  constexpr int totalV4 = BM * K / 4;
  for (int i = tid; i < totalV4; i += 256) {
    int r = i / (K / 4), c = i % (K / 4);
    float4 v = make_float4(0.f, 0.f, 0.f, 0.f);
    if (rowBase + r < M)
      v = ((const float4*)A)[(size_t)(rowBase + r) * (K / 4) + c];
    *(float4*)&As[r * K + c * 4] = v;
  }
  __syncthreads();

  const int tx = tid % CG;
  const int ty = tid / CG;
  float acc[TM][4];
#pragma unroll
  for (int i = 0; i < TM; i++)
    acc[i][0] = acc[i][1] = acc[i][2] = acc[i][3] = 0.f;

  const float4* W4 = (const float4*)W;
  for (int k = 0; k < K; k += 4) {
    float4 w0 = W4[(k + 0) * CG + tx];
    float4 w1 = W4[(k + 1) * CG + tx];
    float4 w2 = W4[(k + 2) * CG + tx];
    float4 w3 = W4[(k + 3) * CG + tx];
#pragma unroll
    for (int i = 0; i < TM; i++) {
      float4 a = *(const float4*)&As[(ty * TM + i) * K + k];
      acc[i][0] += a.x * w0.x + a.y * w1.x + a.z * w2.x + a.w * w3.x;
      acc[i][1] += a.x * w0.y + a.y * w1.y + a.z * w2.y + a.w * w3.y;
      acc[i][2] += a.x * w0.z + a.y * w1.z + a.z * w2.z + a.w * w3.z;
      acc[i][3] += a.x * w0.w + a.y * w1.w + a.z * w2.w + a.w * w3.w;
    }
  }

  float4 bv = ((const float4*)bias)[tx];
#pragma unroll
  for (int i = 0; i < TM; i++) {
    int r = rowBase + ty * TM + i;
    if (r < M) {
      float4 o;
      o.x = fmaxf(acc[i][0] + bv.x, 0.f);
      o.y = fmaxf(acc[i][1] + bv.y, 0.f);
      o.z = fmaxf(acc[i][2] + bv.z, 0.f);
      o.w = fmaxf(acc[i][3] + bv.w, 0.f);
      ((float4*)C)[(size_t)r * CG + tx] = o;
    }
  }
}

// ---------------------------------------------------------------------------
// launch
// ---------------------------------------------------------------------------
extern "C" void kernel_launch(void* const* d_in, const int* in_sizes, int n_in,
                              void* d_out, int out_size, void* d_ws, size_t ws_size,
                              hipStream_t stream) {
  const float* x = (const float*)d_in[0];
  const int* ei = (const int*)d_in[1];
  const int* src = ei;               // edge_index[0]
  const int* dst = ei + EDGES;       // edge_index[1]
  const float* W1 = (const float*)d_in[2];
  const float* b1 = (const float*)d_in[3];
  const float* W2 = (const float*)d_in[4];
  const float* b2 = (const float*)d_in[5];
  const float* W3 = (const float*)d_in[6];
  const float* b3 = (const float*)d_in[7];
  const float* W4 = (const float*)d_in[8];
  const float* b4 = (const float*)d_in[9];
  float* out = (float*)d_out;

  // workspace layout (~110 MB)
  float* bufA = (float*)d_ws;                        // 100000*128 f32 (51.2 MB)
  float* bufB = bufA + (size_t)NODES * 128;          // 100000*128 f32 (51.2 MB)
  int* rowstart = (int*)(bufB + (size_t)NODES * 128);// 100001 ints
  int* deg = rowstart + NODES + 1;                   // 100000 ints
  int* cursor = deg + NODES;                         // 100000 ints (contiguous w/ deg)
  int* bucket = cursor + NODES;                      // 1.6M ints (6.4 MB)
  int* tilesum = bucket + EDGES;                     // 98 ints
  int* tileoff = tilesum + NTILES;                   // 98 ints
  float* bufC = bufA;  // t2 (100000*64) reuses bufA — h1 dead after gather2

  const int eblocks = (EDGES + 255) / 256;
  const int nblocks4 = (NODES + 3) / 4;   // gather: 4 nodes (waves) per block
  const int gblocks = (NODES + 63) / 64;

  // ---- build CSR (once; shared by both layers) ----
  zero_ints<<<(2 * NODES + 255) / 256, 256, 0, stream>>>(deg, 2 * NODES);  // deg+cursor
  hist_dst<<<eblocks, 256, 0, stream>>>(dst, deg);
  tile_sum<<<NTILES, 256, 0, stream>>>(deg, tilesum);
  scan_tiles<<<1, 128, 0, stream>>>(tilesum, tileoff, rowstart);
  tile_scan<<<NTILES, 256, 0, stream>>>(deg, tileoff, rowstart);
  fill_buckets<<<eblocks, 256, 0, stream>>>(src, dst, rowstart, cursor, bucket);

  // ---- layer 1 ----
  gather_sum128<<<nblocks4, 256, 0, stream>>>(x, rowstart, bucket, bufA);            // h_pre1
  gemm_bias_relu<128, 128><<<gblocks, 256, 0, stream>>>(bufA, W1, b1, bufB, NODES);  // t1
  gemm_bias_relu<128, 128><<<gblocks, 256, 0, stream>>>(bufB, W2, b2, bufA, NODES);  // h1 (outer relu fused)

  // ---- layer 2 ----
  gather_sum128<<<nblocks4, 256, 0, stream>>>(bufA, rowstart, bucket, bufB);         // h_pre2
  gemm_bias_relu<128, 64><<<gblocks, 256, 0, stream>>>(bufB, W3, b3, bufC, NODES);   // t2
  gemm_bias_relu<64, 64><<<gblocks, 256, 0, stream>>>(bufC, W4, b4, out, NODES);     // out
}

// Round 4
// 541.414 us; speedup vs baseline: 10.4744x; 1.3137x over previous
//
#include <hip/hip_runtime.h>
#include <hip/hip_bf16.h>

#define NODES 100000
#define EDGES 1600000
#define TILE 1024                           // scan tile (elements)
#define NTILES ((NODES + TILE - 1) / TILE)  // 98

typedef __bf16 bf16x8 __attribute__((ext_vector_type(8)));
typedef float f32x4 __attribute__((ext_vector_type(4)));

__device__ __forceinline__ unsigned short f2b(float f) {
  __hip_bfloat16 h = __float2bfloat16(f);   // RNE
  return __builtin_bit_cast(unsigned short, h);
}
__device__ __forceinline__ float b_lo(unsigned u) { return __uint_as_float(u << 16); }
__device__ __forceinline__ float b_hi(unsigned u) { return __uint_as_float(u & 0xffff0000u); }

// ---------------------------------------------------------------------------
// zero n ints
// ---------------------------------------------------------------------------
__global__ __launch_bounds__(256) void zero_ints(int* __restrict__ p, int n) {
  int i = blockIdx.x * 256 + threadIdx.x;
  if (i < n) p[i] = 0;
}

// ---------------------------------------------------------------------------
// cast x (f32) -> bf16 table, 4 elems/thread
// ---------------------------------------------------------------------------
__global__ __launch_bounds__(256) void cast_x_bf16(const float4* __restrict__ in,
                                                   ushort4* __restrict__ out, int n4) {
  int i = blockIdx.x * 256 + threadIdx.x;
  if (i < n4) {
    float4 v = in[i];
    ushort4 o;
    o.x = f2b(v.x); o.y = f2b(v.y); o.z = f2b(v.z); o.w = f2b(v.w);
    out[i] = o;
  }
}

// ---------------------------------------------------------------------------
// transpose + cast all 4 weight matrices:  Wt[n][k] = (bf16) W[k][n]
// W1:128x128  W2:128x128  W3:128x64  W4:64x64  (K x N row-major)
// ---------------------------------------------------------------------------
__global__ __launch_bounds__(256) void prep_weights(
    const float* __restrict__ W1, const float* __restrict__ W2,
    const float* __restrict__ W3, const float* __restrict__ W4,
    unsigned short* __restrict__ Wt1, unsigned short* __restrict__ Wt2,
    unsigned short* __restrict__ Wt3, unsigned short* __restrict__ Wt4) {
  int i = blockIdx.x * 256 + threadIdx.x;
  if (i < 16384) {                       // Wt1 [128][128]
    int n = i >> 7, k = i & 127;
    Wt1[i] = f2b(W1[k * 128 + n]);
  } else if (i < 32768) {                // Wt2 [128][128]
    int j = i - 16384; int n = j >> 7, k = j & 127;
    Wt2[j] = f2b(W2[k * 128 + n]);
  } else if (i < 40960) {                // Wt3 [64][128]  (K=128,N=64)
    int j = i - 32768; int n = j >> 7, k = j & 127;
    Wt3[j] = f2b(W3[k * 64 + n]);
  } else if (i < 45056) {                // Wt4 [64][64]
    int j = i - 40960; int n = j >> 6, k = j & 63;
    Wt4[j] = f2b(W4[k * 64 + n]);
  }
}

// ---------------------------------------------------------------------------
// CSR build
// ---------------------------------------------------------------------------
__global__ __launch_bounds__(256) void hist_dst(const int* __restrict__ dst,
                                                int* __restrict__ deg) {
  int e = blockIdx.x * 256 + threadIdx.x;
  if (e < EDGES) atomicAdd(&deg[dst[e]], 1);
}

__global__ __launch_bounds__(256) void tile_sum(const int* __restrict__ deg,
                                                int* __restrict__ tilesum) {
  __shared__ int s[256];
  const int t = threadIdx.x;
  const int base = blockIdx.x * TILE + t * 4;
  int sum = 0;
#pragma unroll
  for (int k = 0; k < 4; k++) {
    int i = base + k;
    if (i < NODES) sum += deg[i];
  }
  s[t] = sum;
  __syncthreads();
  for (int off = 128; off > 0; off >>= 1) {
    if (t < off) s[t] += s[t + off];
    __syncthreads();
  }
  if (t == 0) tilesum[blockIdx.x] = s[0];
}

__global__ __launch_bounds__(128) void scan_tiles(const int* __restrict__ tilesum,
                                                  int* __restrict__ tileoff,
                                                  int* __restrict__ rowstart) {
  __shared__ int s[128];
  const int t = threadIdx.x;
  int v = (t < NTILES) ? tilesum[t] : 0;
  s[t] = v;
  __syncthreads();
  for (int off = 1; off < 128; off <<= 1) {
    int u = (t >= off) ? s[t - off] : 0;
    __syncthreads();
    s[t] += u;
    __syncthreads();
  }
  if (t < NTILES) tileoff[t] = s[t] - v;
  if (t == 127) rowstart[NODES] = s[127];
}

__global__ __launch_bounds__(256) void tile_scan(const int* __restrict__ deg,
                                                 const int* __restrict__ tileoff,
                                                 int* __restrict__ rowstart) {
  __shared__ int s[256];
  const int t = threadIdx.x;
  const int base = blockIdx.x * TILE + t * 4;
  int d[4];
  int sum = 0;
#pragma unroll
  for (int k = 0; k < 4; k++) {
    int i = base + k;
    d[k] = (i < NODES) ? deg[i] : 0;
    sum += d[k];
  }
  s[t] = sum;
  __syncthreads();
  for (int off = 1; off < 256; off <<= 1) {
    int u = (t >= off) ? s[t - off] : 0;
    __syncthreads();
    s[t] += u;
    __syncthreads();
  }
  int run = s[t] - sum + tileoff[blockIdx.x];
#pragma unroll
  for (int k = 0; k < 4; k++) {
    int i = base + k;
    if (i < NODES) rowstart[i] = run;
    run += d[k];
  }
}

__global__ __launch_bounds__(256) void fill_buckets(
    const int* __restrict__ src, const int* __restrict__ dst,
    const int* __restrict__ rowstart, int* __restrict__ cursor,
    int* __restrict__ bucket) {
  int e = blockIdx.x * 256 + threadIdx.x;
  if (e >= EDGES) return;
  int d = dst[e];
  int pos = atomicAdd(&cursor[d], 1);
  bucket[rowstart[d] + pos] = src[e];
}

// ---------------------------------------------------------------------------
// bf16 gather aggregation: out[n,:] = x[n,:] + sum_{j in in(n)} x[src_j,:]
// One wave per node; lane owns 2 features (one packed uint). fp32 accumulate.
// ---------------------------------------------------------------------------
__global__ __launch_bounds__(256) void gather_sum_bf16(
    const unsigned* __restrict__ xh, const int* __restrict__ rowstart,
    const int* __restrict__ bucket, unsigned* __restrict__ outh) {
  const int n = blockIdx.x * 4 + (threadIdx.x >> 6);
  if (n >= NODES) return;
  const int lane = threadIdx.x & 63;

  unsigned self = xh[(size_t)n * 64 + lane];
  float ax = b_lo(self), ay = b_hi(self);
  int j = rowstart[n];
  const int end = rowstart[n + 1];
  for (; j + 1 < end; j += 2) {
    unsigned v0 = xh[(size_t)bucket[j] * 64 + lane];
    unsigned v1 = xh[(size_t)bucket[j + 1] * 64 + lane];
    ax += b_lo(v0) + b_lo(v1);
    ay += b_hi(v0) + b_hi(v1);
  }
  if (j < end) {
    unsigned v = xh[(size_t)bucket[j] * 64 + lane];
    ax += b_lo(v);
    ay += b_hi(v);
  }
  outh[(size_t)n * 64 + lane] = ((unsigned)f2b(ay) << 16) | f2b(ax);
}

// ---------------------------------------------------------------------------
// C[M,N] = relu(A[M,K] @ W[K,N] + bias) via bf16 MFMA, fp32 accumulate.
// A: bf16 row-major [M,K].  Wt: bf16 [N,K] (= W^T).  Out bf16 or f32.
// Block: 256 thr (4 waves), BM=64 rows; wave w owns rows w*16..w*16+15,
// all N/16 col-tiles. LDS stride padded +8 bf16.
// ---------------------------------------------------------------------------
template <int K, int N, bool OUT_F32>
__global__ __launch_bounds__(256) void gemm_mfma(
    const unsigned short* __restrict__ A, const unsigned short* __restrict__ Wt,
    const float* __restrict__ bias, void* __restrict__ Cout, int M) {
  constexpr int LDK = K + 8;
  constexpr int NT = N / 16;   // col tiles
  constexpr int KB = K / 32;   // k steps
  __shared__ unsigned short As[64 * LDK];
  __shared__ unsigned short Ws[N * LDK];

  const int tid = threadIdx.x;
  const int wave = tid >> 6;
  const int lane = tid & 63;
  const int q = lane >> 4;
  const int r16 = lane & 15;
  const int rowBase = blockIdx.x * 64;

  // stage A tile (16B chunks, coalesced; zero-pad rows >= M)
  constexpr int ACH = 64 * (K / 8);
  for (int i = tid; i < ACH; i += 256) {
    int rr = i / (K / 8), cc = i % (K / 8);
    uint4 v = make_uint4(0, 0, 0, 0);
    if (rowBase + rr < M)
      v = ((const uint4*)A)[(size_t)(rowBase + rr) * (K / 8) + cc];
    *(uint4*)&As[rr * LDK + cc * 8] = v;
  }
  // stage Wt tile (N x K)
  constexpr int WCH = N * (K / 8);
  for (int i = tid; i < WCH; i += 256) {
    int rr = i / (K / 8), cc = i % (K / 8);
    *(uint4*)&Ws[rr * LDK + cc * 8] = ((const uint4*)Wt)[i];
  }
  __syncthreads();

  f32x4 acc[NT];
#pragma unroll
  for (int c = 0; c < NT; c++) acc[c] = (f32x4){0.f, 0.f, 0.f, 0.f};

  const int arow = wave * 16 + r16;
#pragma unroll
  for (int kb = 0; kb < KB; kb++) {
    bf16x8 a = *(const bf16x8*)&As[arow * LDK + kb * 32 + q * 8];
#pragma unroll
    for (int c = 0; c < NT; c++) {
      bf16x8 b = *(const bf16x8*)&Ws[(c * 16 + r16) * LDK + kb * 32 + q * 8];
      acc[c] = __builtin_amdgcn_mfma_f32_16x16x32_bf16(a, b, acc[c], 0, 0, 0);
    }
  }

  // epilogue: C/D layout row = q*4+reg, col = lane&15
#pragma unroll
  for (int c = 0; c < NT; c++) {
    int col = c * 16 + r16;
    float bv = bias[col];
#pragma unroll
    for (int reg = 0; reg < 4; reg++) {
      int row = rowBase + wave * 16 + q * 4 + reg;
      if (row < M) {
        float v = fmaxf(acc[c][reg] + bv, 0.f);
        if (OUT_F32)
          ((float*)Cout)[(size_t)row * N + col] = v;
        else
          ((unsigned short*)Cout)[(size_t)row * N + col] = f2b(v);
      }
    }
  }
}

// ---------------------------------------------------------------------------
// launch
// ---------------------------------------------------------------------------
extern "C" void kernel_launch(void* const* d_in, const int* in_sizes, int n_in,
                              void* d_out, int out_size, void* d_ws, size_t ws_size,
                              hipStream_t stream) {
  const float* x = (const float*)d_in[0];
  const int* ei = (const int*)d_in[1];
  const int* src = ei;               // edge_index[0]
  const int* dst = ei + EDGES;       // edge_index[1]
  const float* W1 = (const float*)d_in[2];
  const float* b1 = (const float*)d_in[3];
  const float* W2 = (const float*)d_in[4];
  const float* b2 = (const float*)d_in[5];
  const float* W3 = (const float*)d_in[6];
  const float* b3 = (const float*)d_in[7];
  const float* W4 = (const float*)d_in[8];
  const float* b4 = (const float*)d_in[9];
  float* out = (float*)d_out;

  // ---- workspace layout (bytes; all 16B-aligned) ----
  char* ws = (char*)d_ws;
  unsigned short* xh = (unsigned short*)ws;                       // 100000*128 bf16 (25.6 MB)
  unsigned short* hA = xh + (size_t)NODES * 128;                  // 25.6 MB
  unsigned short* hB = hA + (size_t)NODES * 128;                  // 25.6 MB
  unsigned short* tC = hB + (size_t)NODES * 128;                  // 100000*64 bf16 (12.8 MB)
  unsigned short* Wt1 = tC + (size_t)NODES * 64;                  // 128*128
  unsigned short* Wt2 = Wt1 + 128 * 128;
  unsigned short* Wt3 = Wt2 + 128 * 128;                          // 64*128
  unsigned short* Wt4 = Wt3 + 64 * 128;                           // 64*64
  int* rowstart = (int*)(Wt4 + 64 * 64);                          // NODES+1
  int* deg = rowstart + NODES + 1;
  int* cursor = deg + NODES;
  int* bucket = cursor + NODES;                                   // EDGES (6.4 MB)
  int* tilesum = bucket + EDGES;
  int* tileoff = tilesum + NTILES;

  const int eblocks = (EDGES + 255) / 256;
  const int nblocks4 = (NODES + 3) / 4;
  const int gblocks = (NODES + 63) / 64;
  const int n4 = NODES * 128 / 4;

  // ---- prep: casts + CSR (independent work, back-to-back) ----
  cast_x_bf16<<<(n4 + 255) / 256, 256, 0, stream>>>((const float4*)x, (ushort4*)xh, n4);
  prep_weights<<<(45056 + 255) / 256, 256, 0, stream>>>(W1, W2, W3, W4, Wt1, Wt2, Wt3, Wt4);
  zero_ints<<<(2 * NODES + 255) / 256, 256, 0, stream>>>(deg, 2 * NODES);
  hist_dst<<<eblocks, 256, 0, stream>>>(dst, deg);
  tile_sum<<<NTILES, 256, 0, stream>>>(deg, tilesum);
  scan_tiles<<<1, 128, 0, stream>>>(tilesum, tileoff, rowstart);
  tile_scan<<<NTILES, 256, 0, stream>>>(deg, tileoff, rowstart);
  fill_buckets<<<eblocks, 256, 0, stream>>>(src, dst, rowstart, cursor, bucket);

  // ---- layer 1 ----
  gather_sum_bf16<<<nblocks4, 256, 0, stream>>>((const unsigned*)xh, rowstart, bucket,
                                                (unsigned*)hA);                      // h_pre1
  gemm_mfma<128, 128, false><<<gblocks, 256, 0, stream>>>(hA, Wt1, b1, hB, NODES);   // t1
  gemm_mfma<128, 128, false><<<gblocks, 256, 0, stream>>>(hB, Wt2, b2, hA, NODES);   // h1 (outer relu)

  // ---- layer 2 ----
  gather_sum_bf16<<<nblocks4, 256, 0, stream>>>((const unsigned*)hA, rowstart, bucket,
                                                (unsigned*)hB);                      // h_pre2
  gemm_mfma<128, 64, false><<<gblocks, 256, 0, stream>>>(hB, Wt3, b3, tC, NODES);    // t2
  gemm_mfma<64, 64, true><<<gblocks, 256, 0, stream>>>(tC, Wt4, b4, out, NODES);     // out (f32)
}

// Round 5
// 523.153 us; speedup vs baseline: 10.8400x; 1.0349x over previous
//
#include <hip/hip_runtime.h>
#include <hip/hip_bf16.h>

#define NODES 100000
#define EDGES 1600000
#define TILE 1024                           // scan tile (elements)
#define NTILES ((NODES + TILE - 1) / TILE)  // 98

typedef __bf16 bf16x8 __attribute__((ext_vector_type(8)));
typedef float f32x4 __attribute__((ext_vector_type(4)));

__device__ __forceinline__ unsigned short f2b(float f) {
  __hip_bfloat16 h = __float2bfloat16(f);   // RNE
  return __builtin_bit_cast(unsigned short, h);
}
__device__ __forceinline__ float b_lo(unsigned u) { return __uint_as_float(u << 16); }
__device__ __forceinline__ float b_hi(unsigned u) { return __uint_as_float(u & 0xffff0000u); }

// ---------------------------------------------------------------------------
// zero n ints
// ---------------------------------------------------------------------------
__global__ __launch_bounds__(256) void zero_ints(int* __restrict__ p, int n) {
  int i = blockIdx.x * 256 + threadIdx.x;
  if (i < n) p[i] = 0;
}

// ---------------------------------------------------------------------------
// cast x (f32) -> bf16 table, 4 elems/thread
// ---------------------------------------------------------------------------
__global__ __launch_bounds__(256) void cast_x_bf16(const float4* __restrict__ in,
                                                   ushort4* __restrict__ out, int n4) {
  int i = blockIdx.x * 256 + threadIdx.x;
  if (i < n4) {
    float4 v = in[i];
    ushort4 o;
    o.x = f2b(v.x); o.y = f2b(v.y); o.z = f2b(v.z); o.w = f2b(v.w);
    out[i] = o;
  }
}

// ---------------------------------------------------------------------------
// transpose + cast all 4 weight matrices:  Wt[n][k] = (bf16) W[k][n]
// ---------------------------------------------------------------------------
__global__ __launch_bounds__(256) void prep_weights(
    const float* __restrict__ W1, const float* __restrict__ W2,
    const float* __restrict__ W3, const float* __restrict__ W4,
    unsigned short* __restrict__ Wt1, unsigned short* __restrict__ Wt2,
    unsigned short* __restrict__ Wt3, unsigned short* __restrict__ Wt4) {
  int i = blockIdx.x * 256 + threadIdx.x;
  if (i < 16384) {                       // Wt1 [128][128]
    int n = i >> 7, k = i & 127;
    Wt1[i] = f2b(W1[k * 128 + n]);
  } else if (i < 32768) {                // Wt2 [128][128]
    int j = i - 16384; int n = j >> 7, k = j & 127;
    Wt2[j] = f2b(W2[k * 128 + n]);
  } else if (i < 40960) {                // Wt3 [64][128]  (K=128,N=64)
    int j = i - 32768; int n = j >> 7, k = j & 127;
    Wt3[j] = f2b(W3[k * 64 + n]);
  } else if (i < 45056) {                // Wt4 [64][64]
    int j = i - 40960; int n = j >> 6, k = j & 63;
    Wt4[j] = f2b(W4[k * 64 + n]);
  }
}

// ---------------------------------------------------------------------------
// CSR build
// ---------------------------------------------------------------------------
__global__ __launch_bounds__(256) void hist_dst(const int* __restrict__ dst,
                                                int* __restrict__ deg) {
  int e = blockIdx.x * 256 + threadIdx.x;
  if (e < EDGES) atomicAdd(&deg[dst[e]], 1);
}

__global__ __launch_bounds__(256) void tile_sum(const int* __restrict__ deg,
                                                int* __restrict__ tilesum) {
  __shared__ int s[256];
  const int t = threadIdx.x;
  const int base = blockIdx.x * TILE + t * 4;
  int sum = 0;
#pragma unroll
  for (int k = 0; k < 4; k++) {
    int i = base + k;
    if (i < NODES) sum += deg[i];
  }
  s[t] = sum;
  __syncthreads();
  for (int off = 128; off > 0; off >>= 1) {
    if (t < off) s[t] += s[t + off];
    __syncthreads();
  }
  if (t == 0) tilesum[blockIdx.x] = s[0];
}

__global__ __launch_bounds__(128) void scan_tiles(const int* __restrict__ tilesum,
                                                  int* __restrict__ tileoff,
                                                  int* __restrict__ rowstart) {
  __shared__ int s[128];
  const int t = threadIdx.x;
  int v = (t < NTILES) ? tilesum[t] : 0;
  s[t] = v;
  __syncthreads();
  for (int off = 1; off < 128; off <<= 1) {
    int u = (t >= off) ? s[t - off] : 0;
    __syncthreads();
    s[t] += u;
    __syncthreads();
  }
  if (t < NTILES) tileoff[t] = s[t] - v;
  if (t == 127) rowstart[NODES] = s[127];
}

// writes rowstart AND a working copy rowcur (used as fill cursor)
__global__ __launch_bounds__(256) void tile_scan(const int* __restrict__ deg,
                                                 const int* __restrict__ tileoff,
                                                 int* __restrict__ rowstart,
                                                 int* __restrict__ rowcur) {
  __shared__ int s[256];
  const int t = threadIdx.x;
  const int base = blockIdx.x * TILE + t * 4;
  int d[4];
  int sum = 0;
#pragma unroll
  for (int k = 0; k < 4; k++) {
    int i = base + k;
    d[k] = (i < NODES) ? deg[i] : 0;
    sum += d[k];
  }
  s[t] = sum;
  __syncthreads();
  for (int off = 1; off < 256; off <<= 1) {
    int u = (t >= off) ? s[t - off] : 0;
    __syncthreads();
    s[t] += u;
    __syncthreads();
  }
  int run = s[t] - sum + tileoff[blockIdx.x];
#pragma unroll
  for (int k = 0; k < 4; k++) {
    int i = base + k;
    if (i < NODES) { rowstart[i] = run; rowcur[i] = run; }
    run += d[k];
  }
}

__global__ __launch_bounds__(256) void fill_buckets(
    const int* __restrict__ src, const int* __restrict__ dst,
    int* __restrict__ rowcur, int* __restrict__ bucket) {
  int e = blockIdx.x * 256 + threadIdx.x;
  if (e >= EDGES) return;
  int pos = atomicAdd(&rowcur[dst[e]], 1);
  bucket[pos] = src[e];
}

// ---------------------------------------------------------------------------
// bf16 gather aggregation, 4 edges per wave-load:
//   out[n,:] = x[n,:] + sum_{j in in(n)} x[src_j,:]
// One wave per node. Lane group g=lane>>4 takes edge j+g; each lane loads
// uint4 = 8 bf16 features (16 lanes cover the 256B row). fp32 accumulate,
// cross-group combine via two shfl_xor butterflies.
// ---------------------------------------------------------------------------
__global__ __launch_bounds__(256) void gather_sum_bf16(
    const uint4* __restrict__ xq, const int* __restrict__ rowstart,
    const int* __restrict__ bucket, uint4* __restrict__ outq) {
  const int n = blockIdx.x * 4 + (threadIdx.x >> 6);
  if (n >= NODES) return;
  const int lane = threadIdx.x & 63;
  const int g = lane >> 4;
  const int fl = lane & 15;

  float a[8] = {0.f, 0.f, 0.f, 0.f, 0.f, 0.f, 0.f, 0.f};
  if (g == 0) {  // self row counted once
    uint4 v = xq[(size_t)n * 16 + fl];
    a[0] = b_lo(v.x); a[1] = b_hi(v.x);
    a[2] = b_lo(v.y); a[3] = b_hi(v.y);
    a[4] = b_lo(v.z); a[5] = b_hi(v.z);
    a[6] = b_lo(v.w); a[7] = b_hi(v.w);
  }

  const int beg = rowstart[n];
  const int end = rowstart[n + 1];
  for (int j = beg; j < end; j += 4) {
    int e = j + g;
    int idx = (e < end) ? e : (end - 1);  // safe: loop body implies end > beg
    int s = bucket[idx];
    uint4 v = xq[(size_t)s * 16 + fl];
    float m = (e < end) ? 1.f : 0.f;
    a[0] = fmaf(b_lo(v.x), m, a[0]); a[1] = fmaf(b_hi(v.x), m, a[1]);
    a[2] = fmaf(b_lo(v.y), m, a[2]); a[3] = fmaf(b_hi(v.y), m, a[3]);
    a[4] = fmaf(b_lo(v.z), m, a[4]); a[5] = fmaf(b_hi(v.z), m, a[5]);
    a[6] = fmaf(b_lo(v.w), m, a[6]); a[7] = fmaf(b_hi(v.w), m, a[7]);
  }

#pragma unroll
  for (int k = 0; k < 8; k++) {
    a[k] += __shfl_xor(a[k], 16, 64);
    a[k] += __shfl_xor(a[k], 32, 64);
  }

  if (lane < 16) {
    uint4 o;
    o.x = ((unsigned)f2b(a[1]) << 16) | f2b(a[0]);
    o.y = ((unsigned)f2b(a[3]) << 16) | f2b(a[2]);
    o.z = ((unsigned)f2b(a[5]) << 16) | f2b(a[4]);
    o.w = ((unsigned)f2b(a[7]) << 16) | f2b(a[6]);
    outq[(size_t)n * 16 + fl] = o;
  }
}

// ---------------------------------------------------------------------------
// C[M,N] = relu(A[M,K] @ W[K,N] + bias) via bf16 MFMA, fp32 accumulate.
// ---------------------------------------------------------------------------
template <int K, int N, bool OUT_F32>
__global__ __launch_bounds__(256) void gemm_mfma(
    const unsigned short* __restrict__ A, const unsigned short* __restrict__ Wt,
    const float* __restrict__ bias, void* __restrict__ Cout, int M) {
  constexpr int LDK = K + 8;
  constexpr int NT = N / 16;   // col tiles
  constexpr int KB = K / 32;   // k steps
  __shared__ unsigned short As[64 * LDK];
  __shared__ unsigned short Ws[N * LDK];

  const int tid = threadIdx.x;
  const int wave = tid >> 6;
  const int lane = tid & 63;
  const int q = lane >> 4;
  const int r16 = lane & 15;
  const int rowBase = blockIdx.x * 64;

  constexpr int ACH = 64 * (K / 8);
  for (int i = tid; i < ACH; i += 256) {
    int rr = i / (K / 8), cc = i % (K / 8);
    uint4 v = make_uint4(0, 0, 0, 0);
    if (rowBase + rr < M)
      v = ((const uint4*)A)[(size_t)(rowBase + rr) * (K / 8) + cc];
    *(uint4*)&As[rr * LDK + cc * 8] = v;
  }
  constexpr int WCH = N * (K / 8);
  for (int i = tid; i < WCH; i += 256) {
    int rr = i / (K / 8), cc = i % (K / 8);
    *(uint4*)&Ws[rr * LDK + cc * 8] = ((const uint4*)Wt)[i];
  }
  __syncthreads();

  f32x4 acc[NT];
#pragma unroll
  for (int c = 0; c < NT; c++) acc[c] = (f32x4){0.f, 0.f, 0.f, 0.f};

  const int arow = wave * 16 + r16;
#pragma unroll
  for (int kb = 0; kb < KB; kb++) {
    bf16x8 a = *(const bf16x8*)&As[arow * LDK + kb * 32 + q * 8];
#pragma unroll
    for (int c = 0; c < NT; c++) {
      bf16x8 b = *(const bf16x8*)&Ws[(c * 16 + r16) * LDK + kb * 32 + q * 8];
      acc[c] = __builtin_amdgcn_mfma_f32_16x16x32_bf16(a, b, acc[c], 0, 0, 0);
    }
  }

#pragma unroll
  for (int c = 0; c < NT; c++) {
    int col = c * 16 + r16;
    float bv = bias[col];
#pragma unroll
    for (int reg = 0; reg < 4; reg++) {
      int row = rowBase + wave * 16 + q * 4 + reg;
      if (row < M) {
        float v = fmaxf(acc[c][reg] + bv, 0.f);
        if (OUT_F32)
          ((float*)Cout)[(size_t)row * N + col] = v;
        else
          ((unsigned short*)Cout)[(size_t)row * N + col] = f2b(v);
      }
    }
  }
}

// ---------------------------------------------------------------------------
// launch
// ---------------------------------------------------------------------------
extern "C" void kernel_launch(void* const* d_in, const int* in_sizes, int n_in,
                              void* d_out, int out_size, void* d_ws, size_t ws_size,
                              hipStream_t stream) {
  const float* x = (const float*)d_in[0];
  const int* ei = (const int*)d_in[1];
  const int* src = ei;               // edge_index[0]
  const int* dst = ei + EDGES;       // edge_index[1]
  const float* W1 = (const float*)d_in[2];
  const float* b1 = (const float*)d_in[3];
  const float* W2 = (const float*)d_in[4];
  const float* b2 = (const float*)d_in[5];
  const float* W3 = (const float*)d_in[6];
  const float* b3 = (const float*)d_in[7];
  const float* W4 = (const float*)d_in[8];
  const float* b4 = (const float*)d_in[9];
  float* out = (float*)d_out;

  // ---- workspace layout (all 16B-aligned) ----
  char* ws = (char*)d_ws;
  unsigned short* xh = (unsigned short*)ws;                       // 100000*128 bf16 (25.6 MB)
  unsigned short* hA = xh + (size_t)NODES * 128;                  // 25.6 MB
  unsigned short* hB = hA + (size_t)NODES * 128;                  // 25.6 MB
  unsigned short* tC = hB + (size_t)NODES * 128;                  // 100000*64 bf16 (12.8 MB)
  unsigned short* Wt1 = tC + (size_t)NODES * 64;                  // 128*128
  unsigned short* Wt2 = Wt1 + 128 * 128;
  unsigned short* Wt3 = Wt2 + 128 * 128;                          // 64*128
  unsigned short* Wt4 = Wt3 + 64 * 128;                           // 64*64
  int* rowstart = (int*)(Wt4 + 64 * 64);                          // NODES+1
  int* deg = rowstart + NODES + 1;
  int* rowcur = deg + NODES;
  int* bucket = rowcur + NODES;                                   // EDGES (6.4 MB)
  int* tilesum = bucket + EDGES;
  int* tileoff = tilesum + NTILES;

  const int eblocks = (EDGES + 255) / 256;
  const int nblocks4 = (NODES + 3) / 4;
  const int gblocks = (NODES + 63) / 64;
  const int n4 = NODES * 128 / 4;

  // ---- prep: casts + CSR ----
  cast_x_bf16<<<(n4 + 255) / 256, 256, 0, stream>>>((const float4*)x, (ushort4*)xh, n4);
  prep_weights<<<(45056 + 255) / 256, 256, 0, stream>>>(W1, W2, W3, W4, Wt1, Wt2, Wt3, Wt4);
  zero_ints<<<(NODES + 255) / 256, 256, 0, stream>>>(deg, NODES);
  hist_dst<<<eblocks, 256, 0, stream>>>(dst, deg);
  tile_sum<<<NTILES, 256, 0, stream>>>(deg, tilesum);
  scan_tiles<<<1, 128, 0, stream>>>(tilesum, tileoff, rowstart);
  tile_scan<<<NTILES, 256, 0, stream>>>(deg, tileoff, rowstart, rowcur);
  fill_buckets<<<eblocks, 256, 0, stream>>>(src, dst, rowcur, bucket);

  // ---- layer 1 ----
  gather_sum_bf16<<<nblocks4, 256, 0, stream>>>((const uint4*)xh, rowstart, bucket,
                                                (uint4*)hA);                         // h_pre1
  gemm_mfma<128, 128, false><<<gblocks, 256, 0, stream>>>(hA, Wt1, b1, hB, NODES);   // t1
  gemm_mfma<128, 128, false><<<gblocks, 256, 0, stream>>>(hB, Wt2, b2, hA, NODES);   // h1 (outer relu)

  // ---- layer 2 ----
  gather_sum_bf16<<<nblocks4, 256, 0, stream>>>((const uint4*)hA, rowstart, bucket,
                                                (uint4*)hB);                         // h_pre2
  gemm_mfma<128, 64, false><<<gblocks, 256, 0, stream>>>(hB, Wt3, b3, tC, NODES);    // t2
  gemm_mfma<64, 64, true><<<gblocks, 256, 0, stream>>>(tC, Wt4, b4, out, NODES);     // out (f32)
}

// Round 6
// 407.887 us; speedup vs baseline: 13.9034x; 1.2826x over previous
//
#include <hip/hip_runtime.h>
#include <hip/hip_bf16.h>

#define NODES 100000
#define EDGES 1600000
#define NBINS ((NODES + 255) >> 8)              // 391 coarse bins, 256 nodes each
#define BINCAP 8192                             // LDS capacity per bin (mean 4092, 64 sigma)
#define PB_BLOCKS 128
#define PB_CHUNK ((EDGES + PB_BLOCKS - 1) / PB_BLOCKS)  // 12500 edges per block

typedef __bf16 bf16x8 __attribute__((ext_vector_type(8)));
typedef float f32x4 __attribute__((ext_vector_type(4)));

__device__ __forceinline__ unsigned short f2b(float f) {
  __hip_bfloat16 h = __float2bfloat16(f);   // RNE
  return __builtin_bit_cast(unsigned short, h);
}
__device__ __forceinline__ float b_lo(unsigned u) { return __uint_as_float(u << 16); }
__device__ __forceinline__ float b_hi(unsigned u) { return __uint_as_float(u & 0xffff0000u); }

// ---------------------------------------------------------------------------
// zero n ints
// ---------------------------------------------------------------------------
__global__ __launch_bounds__(256) void zero_ints(int* __restrict__ p, int n) {
  int i = blockIdx.x * 256 + threadIdx.x;
  if (i < n) p[i] = 0;
}

// ---------------------------------------------------------------------------
// cast x (f32) -> bf16 table
// ---------------------------------------------------------------------------
__global__ __launch_bounds__(256) void cast_x_bf16(const float4* __restrict__ in,
                                                   ushort4* __restrict__ out, int n4) {
  int i = blockIdx.x * 256 + threadIdx.x;
  if (i < n4) {
    float4 v = in[i];
    ushort4 o;
    o.x = f2b(v.x); o.y = f2b(v.y); o.z = f2b(v.z); o.w = f2b(v.w);
    out[i] = o;
  }
}

// ---------------------------------------------------------------------------
// transpose + cast all 4 weight matrices:  Wt[n][k] = (bf16) W[k][n]
// ---------------------------------------------------------------------------
__global__ __launch_bounds__(256) void prep_weights(
    const float* __restrict__ W1, const float* __restrict__ W2,
    const float* __restrict__ W3, const float* __restrict__ W4,
    unsigned short* __restrict__ Wt1, unsigned short* __restrict__ Wt2,
    unsigned short* __restrict__ Wt3, unsigned short* __restrict__ Wt4) {
  int i = blockIdx.x * 256 + threadIdx.x;
  if (i < 16384) {                       // Wt1 [128][128]
    int n = i >> 7, k = i & 127;
    Wt1[i] = f2b(W1[k * 128 + n]);
  } else if (i < 32768) {                // Wt2 [128][128]
    int j = i - 16384; int n = j >> 7, k = j & 127;
    Wt2[j] = f2b(W2[k * 128 + n]);
  } else if (i < 40960) {                // Wt3 [64][128]  (K=128,N=64)
    int j = i - 32768; int n = j >> 7, k = j & 127;
    Wt3[j] = f2b(W3[k * 64 + n]);
  } else if (i < 45056) {                // Wt4 [64][64]
    int j = i - 40960; int n = j >> 6, k = j & 63;
    Wt4[j] = f2b(W4[k * 64 + n]);
  }
}

// ---------------------------------------------------------------------------
// CSR build, pass A: coarse bin counts (LDS histogram per block)
// ---------------------------------------------------------------------------
__global__ __launch_bounds__(256) void bin_count(const int* __restrict__ dst,
                                                 int* __restrict__ binCount) {
  __shared__ int h[NBINS];
  for (int i = threadIdx.x; i < NBINS; i += 256) h[i] = 0;
  __syncthreads();
  const int beg = blockIdx.x * PB_CHUNK;
  const int end = min(beg + PB_CHUNK, EDGES);
  for (int e = beg + threadIdx.x; e < end; e += 256)
    atomicAdd(&h[dst[e] >> 8], 1);
  __syncthreads();
  for (int i = threadIdx.x; i < NBINS; i += 256)
    if (h[i]) atomicAdd(&binCount[i], h[i]);
}

// ---------------------------------------------------------------------------
// CSR build, pass A2: scan 391 bin counts -> binStart[392], binCur
// ---------------------------------------------------------------------------
__global__ __launch_bounds__(512) void scan_bins(const int* __restrict__ binCount,
                                                 int* __restrict__ binStart,
                                                 int* __restrict__ binCur,
                                                 int* __restrict__ rowstart) {
  __shared__ int s[512];
  const int t = threadIdx.x;
  int v = (t < NBINS) ? binCount[t] : 0;
  s[t] = v;
  __syncthreads();
  for (int off = 1; off < 512; off <<= 1) {
    int u = (t >= off) ? s[t - off] : 0;
    __syncthreads();
    s[t] += u;
    __syncthreads();
  }
  if (t < NBINS) {
    int ex = s[t] - v;
    binStart[t] = ex;
    binCur[t] = ex;
  }
  if (t == 0) {
    binStart[NBINS] = EDGES;
    rowstart[NODES] = EDGES;
  }
}

// ---------------------------------------------------------------------------
// CSR build, pass B: scatter edges into coarse bins.
// Each block reserves one contiguous range per bin (1 global atomic), then
// writes packed entries (dstLocal<<17 | src) in ~50-entry runs.
// ---------------------------------------------------------------------------
__global__ __launch_bounds__(256) void bin_scatter(const int* __restrict__ src,
                                                   const int* __restrict__ dst,
                                                   int* __restrict__ binCur,
                                                   unsigned* __restrict__ coarse) {
  __shared__ int h[NBINS];
  __shared__ int base[NBINS];
  const int beg = blockIdx.x * PB_CHUNK;
  const int end = min(beg + PB_CHUNK, EDGES);

  for (int i = threadIdx.x; i < NBINS; i += 256) h[i] = 0;
  __syncthreads();
  for (int e = beg + threadIdx.x; e < end; e += 256)
    atomicAdd(&h[dst[e] >> 8], 1);
  __syncthreads();
  for (int i = threadIdx.x; i < NBINS; i += 256) {
    int c = h[i];
    base[i] = c ? atomicAdd(&binCur[i], c) : 0;
  }
  __syncthreads();
  for (int i = threadIdx.x; i < NBINS; i += 256) h[i] = 0;  // reuse as local cursor
  __syncthreads();
  for (int e = beg + threadIdx.x; e < end; e += 256) {
    int d = dst[e];
    int b = d >> 8;
    int pos = base[b] + atomicAdd(&h[b], 1);
    coarse[pos] = (unsigned)src[e] | ((unsigned)(d & 255) << 17);
  }
}

// ---------------------------------------------------------------------------
// CSR build, pass C: one block per bin. LDS counting-sort of the bin's
// entries by node; writes rowstart (coalesced) and the sorted bucket slice
// (coalesced, full lines, single writer region).
// ---------------------------------------------------------------------------
__global__ __launch_bounds__(256) void bin_fine(const unsigned* __restrict__ coarse,
                                                const int* __restrict__ binStart,
                                                int* __restrict__ rowstart,
                                                int* __restrict__ bucket) {
  __shared__ unsigned ent[BINCAP];
  __shared__ unsigned obuf[BINCAP];
  __shared__ int deg[256];
  __shared__ int pre[256];
  const int b = blockIdx.x;
  const int t = threadIdx.x;
  const int s0 = binStart[b];
  const int nE = binStart[b + 1] - s0;
  const int binBase = b << 8;

  deg[t] = 0;
  __syncthreads();
  for (int i = t; i < nE; i += 256) {
    unsigned e = coarse[s0 + i];
    ent[i] = e;
    atomicAdd(&deg[e >> 17], 1);
  }
  __syncthreads();
  // exclusive scan of deg over 256 nodes
  int v = deg[t];
  pre[t] = v;
  __syncthreads();
  for (int off = 1; off < 256; off <<= 1) {
    int u = (t >= off) ? pre[t - off] : 0;
    __syncthreads();
    pre[t] += u;
    __syncthreads();
  }
  int ex = pre[t] - v;
  if (binBase + t < NODES) rowstart[binBase + t] = s0 + ex;
  deg[t] = ex;  // reuse as cursor
  __syncthreads();
  for (int i = t; i < nE; i += 256) {
    unsigned e = ent[i];
    int pos = atomicAdd(&deg[e >> 17], 1);
    obuf[pos] = e & 0x1FFFFu;
  }
  __syncthreads();
  for (int i = t; i < nE; i += 256) bucket[s0 + i] = (int)obuf[i];
}

// ---------------------------------------------------------------------------
// bf16 gather aggregation, 4 edges per wave-load (see R5).
// ---------------------------------------------------------------------------
__global__ __launch_bounds__(256) void gather_sum_bf16(
    const uint4* __restrict__ xq, const int* __restrict__ rowstart,
    const int* __restrict__ bucket, uint4* __restrict__ outq) {
  const int n = blockIdx.x * 4 + (threadIdx.x >> 6);
  if (n >= NODES) return;
  const int lane = threadIdx.x & 63;
  const int g = lane >> 4;
  const int fl = lane & 15;

  float a[8] = {0.f, 0.f, 0.f, 0.f, 0.f, 0.f, 0.f, 0.f};
  if (g == 0) {  // self row counted once
    uint4 v = xq[(size_t)n * 16 + fl];
    a[0] = b_lo(v.x); a[1] = b_hi(v.x);
    a[2] = b_lo(v.y); a[3] = b_hi(v.y);
    a[4] = b_lo(v.z); a[5] = b_hi(v.z);
    a[6] = b_lo(v.w); a[7] = b_hi(v.w);
  }

  const int beg = rowstart[n];
  const int end = rowstart[n + 1];
  for (int j = beg; j < end; j += 4) {
    int e = j + g;
    int idx = (e < end) ? e : (end - 1);  // safe: loop body implies end > beg
    int s = bucket[idx];
    uint4 v = xq[(size_t)s * 16 + fl];
    float m = (e < end) ? 1.f : 0.f;
    a[0] = fmaf(b_lo(v.x), m, a[0]); a[1] = fmaf(b_hi(v.x), m, a[1]);
    a[2] = fmaf(b_lo(v.y), m, a[2]); a[3] = fmaf(b_hi(v.y), m, a[3]);
    a[4] = fmaf(b_lo(v.z), m, a[4]); a[5] = fmaf(b_hi(v.z), m, a[5]);
    a[6] = fmaf(b_lo(v.w), m, a[6]); a[7] = fmaf(b_hi(v.w), m, a[7]);
  }

#pragma unroll
  for (int k = 0; k < 8; k++) {
    a[k] += __shfl_xor(a[k], 16, 64);
    a[k] += __shfl_xor(a[k], 32, 64);
  }

  if (lane < 16) {
    uint4 o;
    o.x = ((unsigned)f2b(a[1]) << 16) | f2b(a[0]);
    o.y = ((unsigned)f2b(a[3]) << 16) | f2b(a[2]);
    o.z = ((unsigned)f2b(a[5]) << 16) | f2b(a[4]);
    o.w = ((unsigned)f2b(a[7]) << 16) | f2b(a[6]);
    outq[(size_t)n * 16 + fl] = o;
  }
}

// ---------------------------------------------------------------------------
// C[M,N] = relu(A[M,K] @ W[K,N] + bias) via bf16 MFMA, fp32 accumulate.
// ---------------------------------------------------------------------------
template <int K, int N, bool OUT_F32>
__global__ __launch_bounds__(256) void gemm_mfma(
    const unsigned short* __restrict__ A, const unsigned short* __restrict__ Wt,
    const float* __restrict__ bias, void* __restrict__ Cout, int M) {
  constexpr int LDK = K + 8;
  constexpr int NT = N / 16;   // col tiles
  constexpr int KB = K / 32;   // k steps
  __shared__ unsigned short As[64 * LDK];
  __shared__ unsigned short Ws[N * LDK];

  const int tid = threadIdx.x;
  const int wave = tid >> 6;
  const int lane = tid & 63;
  const int q = lane >> 4;
  const int r16 = lane & 15;
  const int rowBase = blockIdx.x * 64;

  constexpr int ACH = 64 * (K / 8);
  for (int i = tid; i < ACH; i += 256) {
    int rr = i / (K / 8), cc = i % (K / 8);
    uint4 v = make_uint4(0, 0, 0, 0);
    if (rowBase + rr < M)
      v = ((const uint4*)A)[(size_t)(rowBase + rr) * (K / 8) + cc];
    *(uint4*)&As[rr * LDK + cc * 8] = v;
  }
  constexpr int WCH = N * (K / 8);
  for (int i = tid; i < WCH; i += 256) {
    int rr = i / (K / 8), cc = i % (K / 8);
    *(uint4*)&Ws[rr * LDK + cc * 8] = ((const uint4*)Wt)[i];
  }
  __syncthreads();

  f32x4 acc[NT];
#pragma unroll
  for (int c = 0; c < NT; c++) acc[c] = (f32x4){0.f, 0.f, 0.f, 0.f};

  const int arow = wave * 16 + r16;
#pragma unroll
  for (int kb = 0; kb < KB; kb++) {
    bf16x8 a = *(const bf16x8*)&As[arow * LDK + kb * 32 + q * 8];
#pragma unroll
    for (int c = 0; c < NT; c++) {
      bf16x8 b = *(const bf16x8*)&Ws[(c * 16 + r16) * LDK + kb * 32 + q * 8];
      acc[c] = __builtin_amdgcn_mfma_f32_16x16x32_bf16(a, b, acc[c], 0, 0, 0);
    }
  }

#pragma unroll
  for (int c = 0; c < NT; c++) {
    int col = c * 16 + r16;
    float bv = bias[col];
#pragma unroll
    for (int reg = 0; reg < 4; reg++) {
      int row = rowBase + wave * 16 + q * 4 + reg;
      if (row < M) {
        float v = fmaxf(acc[c][reg] + bv, 0.f);
        if (OUT_F32)
          ((float*)Cout)[(size_t)row * N + col] = v;
        else
          ((unsigned short*)Cout)[(size_t)row * N + col] = f2b(v);
      }
    }
  }
}

// ---------------------------------------------------------------------------
// launch
// ---------------------------------------------------------------------------
extern "C" void kernel_launch(void* const* d_in, const int* in_sizes, int n_in,
                              void* d_out, int out_size, void* d_ws, size_t ws_size,
                              hipStream_t stream) {
  const float* x = (const float*)d_in[0];
  const int* ei = (const int*)d_in[1];
  const int* src = ei;               // edge_index[0]
  const int* dst = ei + EDGES;       // edge_index[1]
  const float* W1 = (const float*)d_in[2];
  const float* b1 = (const float*)d_in[3];
  const float* W2 = (const float*)d_in[4];
  const float* b2 = (const float*)d_in[5];
  const float* W3 = (const float*)d_in[6];
  const float* b3 = (const float*)d_in[7];
  const float* W4 = (const float*)d_in[8];
  const float* b4 = (const float*)d_in[9];
  float* out = (float*)d_out;

  // ---- workspace layout (all 16B-aligned) ----
  char* ws = (char*)d_ws;
  unsigned short* xh = (unsigned short*)ws;                       // 100000*128 bf16 (25.6 MB)
  unsigned short* hA = xh + (size_t)NODES * 128;                  // 25.6 MB
  unsigned short* hB = hA + (size_t)NODES * 128;                  // 25.6 MB
  unsigned short* tC = hB + (size_t)NODES * 128;                  // 100000*64 bf16 (12.8 MB)
  unsigned short* Wt1 = tC + (size_t)NODES * 64;                  // 128*128
  unsigned short* Wt2 = Wt1 + 128 * 128;
  unsigned short* Wt3 = Wt2 + 128 * 128;                          // 64*128
  unsigned short* Wt4 = Wt3 + 64 * 128;                           // 64*64
  int* rowstart = (int*)(Wt4 + 64 * 64);                          // NODES+1
  int* binCount = rowstart + NODES + 1;                           // NBINS
  int* binStart = binCount + NBINS;                               // NBINS+1
  int* binCur = binStart + NBINS + 1;                             // NBINS
  unsigned* coarse = (unsigned*)(binCur + NBINS);                 // EDGES (6.4 MB)
  int* bucket = (int*)(coarse + EDGES);                           // EDGES (6.4 MB)

  const int nblocks4 = (NODES + 3) / 4;
  const int gblocks = (NODES + 63) / 64;
  const int n4 = NODES * 128 / 4;

  // ---- prep: casts + binned CSR build ----
  cast_x_bf16<<<(n4 + 255) / 256, 256, 0, stream>>>((const float4*)x, (ushort4*)xh, n4);
  prep_weights<<<(45056 + 255) / 256, 256, 0, stream>>>(W1, W2, W3, W4, Wt1, Wt2, Wt3, Wt4);
  zero_ints<<<(NBINS + 255) / 256, 256, 0, stream>>>(binCount, NBINS);
  bin_count<<<PB_BLOCKS, 256, 0, stream>>>(dst, binCount);
  scan_bins<<<1, 512, 0, stream>>>(binCount, binStart, binCur, rowstart);
  bin_scatter<<<PB_BLOCKS, 256, 0, stream>>>(src, dst, binCur, coarse);
  bin_fine<<<NBINS, 256, 0, stream>>>(coarse, binStart, rowstart, bucket);

  // ---- layer 1 ----
  gather_sum_bf16<<<nblocks4, 256, 0, stream>>>((const uint4*)xh, rowstart, bucket,
                                                (uint4*)hA);                         // h_pre1
  gemm_mfma<128, 128, false><<<gblocks, 256, 0, stream>>>(hA, Wt1, b1, hB, NODES);   // t1
  gemm_mfma<128, 128, false><<<gblocks, 256, 0, stream>>>(hB, Wt2, b2, hA, NODES);   // h1 (outer relu)

  // ---- layer 2 ----
  gather_sum_bf16<<<nblocks4, 256, 0, stream>>>((const uint4*)hA, rowstart, bucket,
                                                (uint4*)hB);                         // h_pre2
  gemm_mfma<128, 64, false><<<gblocks, 256, 0, stream>>>(hB, Wt3, b3, tC, NODES);    // t2
  gemm_mfma<64, 64, true><<<gblocks, 256, 0, stream>>>(tC, Wt4, b4, out, NODES);     // out (f32)
}